// Round 1
// baseline (364.732 us; speedup 1.0000x reference)
//
#include <hip/hip_runtime.h>

// OptPosEncVol R3: spatially-sorted trilinear gather.
// Key counter evidence (R2): interp FETCH_SIZE=307MB vs ~25MB compulsory
// (coords in [0,1) -> only upper octant of grid touched, 9.2MB hot set),
// 4.4 TB/s = random-256B ceiling. Fix: counting-sort points by 4^3 brick so
// consecutive waves share a 32KB L2/L1-resident footprint; bbox-filter the
// transpose to the active octant.

#define CODE_NUM 64
#define CODE_CHANNEL 64
#define TABLE (CODE_NUM * CODE_NUM * CODE_NUM)  // 262144
#define NBINS 4096                              // 16^3 coarse cells (4-cell bricks)

// ---------------- aux: init ----------------
__global__ __launch_bounds__(256) void init_k(int* __restrict__ hist, int* __restrict__ bbox) {
    const int t = blockIdx.x * 256 + threadIdx.x;
    for (int i = t; i < NBINS; i += gridDim.x * 256) hist[i] = 0;
    if (t == 0) {
        bbox[0] = 0x7fffffff; bbox[1] = (int)0x80000000;  // ymin, ymax
        bbox[2] = 0x7fffffff; bbox[3] = (int)0x80000000;  // zmin, zmax
    }
}

__device__ __forceinline__ int cell_bin(float x, float y, float z,
                                        int& ix, int& iy, int& iz) {
    ix = (int)floorf((x + 1.0f) * ((CODE_NUM - 1) * 0.5f));
    iy = (int)floorf((y + 1.0f) * ((CODE_NUM - 1) * 0.5f));
    iz = (int)floorf((z + 1.0f) * ((CODE_NUM - 1) * 0.5f));
    const int cx = min(max(ix, 0), 63) >> 2;
    const int cy = min(max(iy, 0), 63) >> 2;
    const int cz = min(max(iz, 0), 63) >> 2;
    return cx | (cy << 4) | (cz << 8);
}

// ---------------- pass 1: histogram + bbox ----------------
__global__ __launch_bounds__(256) void hist_bbox_k(const float* __restrict__ coords, int npoints,
                                                   int* __restrict__ hist, int* __restrict__ bbox) {
    __shared__ int lh[NBINS];
    __shared__ int lb[4];
    for (int i = threadIdx.x; i < NBINS; i += 256) lh[i] = 0;
    if (threadIdx.x == 0) {
        lb[0] = 0x7fffffff; lb[1] = (int)0x80000000;
        lb[2] = 0x7fffffff; lb[3] = (int)0x80000000;
    }
    __syncthreads();
    int ymin = 0x7fffffff, ymax = (int)0x80000000;
    int zmin = 0x7fffffff, zmax = (int)0x80000000;
    const int stride = gridDim.x * 256;
    for (int p = blockIdx.x * 256 + threadIdx.x; p < npoints; p += stride) {
        const float x = coords[p * 3 + 0];
        const float y = coords[p * 3 + 1];
        const float z = coords[p * 3 + 2];
        int ix, iy, iz;
        const int bin = cell_bin(x, y, z, ix, iy, iz);
        atomicAdd(&lh[bin], 1);
        ymin = min(ymin, iy); ymax = max(ymax, iy);
        zmin = min(zmin, iz); zmax = max(zmax, iz);
    }
    atomicMin(&lb[0], ymin); atomicMax(&lb[1], ymax);
    atomicMin(&lb[2], zmin); atomicMax(&lb[3], zmax);
    __syncthreads();
    for (int i = threadIdx.x; i < NBINS; i += 256) {
        const int c = lh[i];
        if (c) atomicAdd(&hist[i], c);
    }
    if (threadIdx.x == 0) {
        atomicMin(&bbox[0], lb[0]); atomicMax(&bbox[1], lb[1]);
        atomicMin(&bbox[2], lb[2]); atomicMax(&bbox[3], lb[3]);
    }
}

// ---------------- pass 2: exclusive scan (one wave, 64 lanes x 64 bins) ----------------
__global__ __launch_bounds__(64) void scan_k(const int* __restrict__ hist, int* __restrict__ cursor) {
    const int l = threadIdx.x;  // 0..63
    int s = 0;
#pragma unroll 1
    for (int i = 0; i < 64; ++i) s += hist[l * 64 + i];
    int inc = s;
#pragma unroll
    for (int d = 1; d < 64; d <<= 1) {
        const int u = __shfl_up(inc, d, 64);
        if (l >= d) inc += u;
    }
    int run = inc - s;  // exclusive base for this lane's 64 bins
#pragma unroll 1
    for (int i = 0; i < 64; ++i) {
        cursor[l * 64 + i] = run;
        run += hist[l * 64 + i];
    }
}

// ---------------- pass 3: scatter points into sorted order ----------------
__global__ __launch_bounds__(256) void scatter_k(const float* __restrict__ coords, int npoints,
                                                 int* __restrict__ cursor, float4* __restrict__ sorted) {
    const int stride = gridDim.x * 256;
    for (int p = blockIdx.x * 256 + threadIdx.x; p < npoints; p += stride) {
        const float x = coords[p * 3 + 0];
        const float y = coords[p * 3 + 1];
        const float z = coords[p * 3 + 2];
        int ix, iy, iz;
        const int bin = cell_bin(x, y, z, ix, iy, iz);
        const int slot = atomicAdd(&cursor[bin], 1);
        sorted[slot] = make_float4(x, y, z, __int_as_float(p));
    }
}

// ---------------- transpose, bbox-filtered ----------------
// One block transposes a 64t x 64c tile (t = x + 64y + 4096z; block covers full
// x-row at fixed y,z). Skip rows outside [ymin, ymax+1] x [zmin, zmax+1]
// (corner gathers reach +1 in each axis; x is always fully covered).
__global__ __launch_bounds__(256) void transpose_bb_k(const float* __restrict__ src,
                                                      float* __restrict__ dst,
                                                      const int* __restrict__ bbox) {
    const int t0 = blockIdx.x * 64;
    const int y = (t0 >> 6) & 63;
    const int z = t0 >> 12;
    if (y < bbox[0] || y > bbox[1] + 1 || z < bbox[2] || z > bbox[3] + 1) return;

    __shared__ float tile[64 * 65];
    const int j = threadIdx.x;
#pragma unroll
    for (int i = 0; i < 4; ++i) {
        const int q = (i << 8) | j;
        const int c = q >> 4;
        const int tc4 = q & 15;
        const float4 v = *(const float4*)(src + (size_t)c * TABLE + t0 + (tc4 << 2));
        tile[((tc4 << 2) + 0) * 65 + c] = v.x;
        tile[((tc4 << 2) + 1) * 65 + c] = v.y;
        tile[((tc4 << 2) + 2) * 65 + c] = v.z;
        tile[((tc4 << 2) + 3) * 65 + c] = v.w;
    }
    __syncthreads();
#pragma unroll
    for (int i = 0; i < 4; ++i) {
        const int q = (i << 8) | j;
        const int t = q >> 4;
        const int c4 = q & 15;
        float4 v;
        v.x = tile[t * 65 + (c4 << 2) + 0];
        v.y = tile[t * 65 + (c4 << 2) + 1];
        v.z = tile[t * 65 + (c4 << 2) + 2];
        v.w = tile[t * 65 + (c4 << 2) + 3];
        *(float4*)(dst + (size_t)(t0 + t) * 64 + (c4 << 2)) = v;
    }
}

// Unfiltered transpose (legacy path when ws only fits the table).
__global__ __launch_bounds__(256) void transpose_k(const float* __restrict__ src,
                                                   float* __restrict__ dst) {
    __shared__ float tile[64 * 65];
    const int t0 = blockIdx.x * 64;
    const int j = threadIdx.x;
#pragma unroll
    for (int i = 0; i < 4; ++i) {
        const int q = (i << 8) | j;
        const int c = q >> 4;
        const int tc4 = q & 15;
        const float4 v = *(const float4*)(src + (size_t)c * TABLE + t0 + (tc4 << 2));
        tile[((tc4 << 2) + 0) * 65 + c] = v.x;
        tile[((tc4 << 2) + 1) * 65 + c] = v.y;
        tile[((tc4 << 2) + 2) * 65 + c] = v.z;
        tile[((tc4 << 2) + 3) * 65 + c] = v.w;
    }
    __syncthreads();
#pragma unroll
    for (int i = 0; i < 4; ++i) {
        const int q = (i << 8) | j;
        const int t = q >> 4;
        const int c4 = q & 15;
        float4 v;
        v.x = tile[t * 65 + (c4 << 2) + 0];
        v.y = tile[t * 65 + (c4 << 2) + 1];
        v.z = tile[t * 65 + (c4 << 2) + 2];
        v.w = tile[t * 65 + (c4 << 2) + 3];
        *(float4*)(dst + (size_t)(t0 + t) * 64 + (c4 << 2)) = v;
    }
}

// ---------------- pass 4: interpolation over the sorted array ----------------
// 4 points per wave: lane l -> point l>>4, channels 4*(l&15)..+3. Each corner
// gather is 16 lanes x 16B = one 256B row; sorted order makes consecutive
// waves hit the same ~32KB brick footprint (L1/L2 resident). Output is
// scattered by original point index (256B contiguous per point).
__global__ __launch_bounds__(256) void interp4s_k(const float4* __restrict__ sorted,
                                                  const float* __restrict__ table,
                                                  const int* __restrict__ idxp,
                                                  float* __restrict__ out,
                                                  int npoints) {
    unsigned bid = blockIdx.x;
    const unsigned nb = gridDim.x;
    if ((nb & 7u) == 0u) {  // XCD-chunked swizzle: each XCD owns a contiguous sorted range
        const unsigned c = nb >> 3;
        bid = (bid & 7u) * c + (bid >> 3);
    }
    const int lane = threadIdx.x & 63;
    const int sub = lane >> 4;
    const int cg = lane & 15;
    const int p = (int)(bid * 16u + ((threadIdx.x >> 6) << 2) + (unsigned)sub);
    if (p >= npoints) return;

    const int offset = idxp[0] * TABLE;
    const float4 s4 = sorted[p];
    const int op = __float_as_int(s4.w);

    const float sx = (s4.x + 1.0f) * ((CODE_NUM - 1) * 0.5f);
    const float sy = (s4.y + 1.0f) * ((CODE_NUM - 1) * 0.5f);
    const float sz = (s4.z + 1.0f) * ((CODE_NUM - 1) * 0.5f);
    const float fx = floorf(sx), fy = floorf(sy), fz = floorf(sz);
    const float rx = sx - fx, ry = sy - fy, rz = sz - fz;
    const int ix = (int)fx, iy = (int)fy, iz = (int)fz;
    const int base = offset + ix + iy * CODE_NUM + iz * (CODE_NUM * CODE_NUM);

    const float wx[2] = {1.0f - rx, rx};
    const float wy[2] = {1.0f - ry, ry};
    const float wz[2] = {1.0f - rz, rz};

    const char* tp = (const char*)table;
    const int cgoff = cg << 4;

    float4 acc = make_float4(0.f, 0.f, 0.f, 0.f);
#pragma unroll
    for (int k = 0; k < 8; ++k) {
        const int a = k & 1, b = (k >> 1) & 1, c = (k >> 2) & 1;
        const int idx = base + a + b * CODE_NUM + c * (CODE_NUM * CODE_NUM);
        const float w = wx[a] * wy[b] * wz[c];
        const float4 v = *(const float4*)(tp + ((size_t)(unsigned)(idx << 8) + cgoff));
        acc.x = fmaf(w, v.x, acc.x);
        acc.y = fmaf(w, v.y, acc.y);
        acc.z = fmaf(w, v.z, acc.z);
        acc.w = fmaf(w, v.w, acc.w);
    }
    *(float4*)(out + (size_t)op * CODE_CHANNEL + (cg << 2)) = acc;
}

// ---------------- legacy unsorted interp (ws fits table only) ----------------
__global__ __launch_bounds__(256) void interp4_k(const float* __restrict__ coords,
                                                 const float* __restrict__ table,
                                                 const int* __restrict__ idxp,
                                                 float* __restrict__ out,
                                                 int npoints) {
    const unsigned tid = blockIdx.x * 256u + threadIdx.x;
    const int lane = threadIdx.x & 63;
    const int sub = lane >> 4;
    const int cg = lane & 15;
    const int p = (int)((tid >> 6) * 4u + (unsigned)sub);
    if (p >= npoints) return;

    const int offset = idxp[0] * TABLE;
    const float sx = (coords[p * 3 + 0] + 1.0f) * ((CODE_NUM - 1) * 0.5f);
    const float sy = (coords[p * 3 + 1] + 1.0f) * ((CODE_NUM - 1) * 0.5f);
    const float sz = (coords[p * 3 + 2] + 1.0f) * ((CODE_NUM - 1) * 0.5f);
    const float fx = floorf(sx), fy = floorf(sy), fz = floorf(sz);
    const float rx = sx - fx, ry = sy - fy, rz = sz - fz;
    const int ix = (int)fx, iy = (int)fy, iz = (int)fz;
    const int base = offset + ix + iy * CODE_NUM + iz * (CODE_NUM * CODE_NUM);
    const float wx[2] = {1.0f - rx, rx};
    const float wy[2] = {1.0f - ry, ry};
    const float wz[2] = {1.0f - rz, rz};
    const char* tp = (const char*)table;
    const int cgoff = cg << 4;
    float4 acc = make_float4(0.f, 0.f, 0.f, 0.f);
#pragma unroll
    for (int k = 0; k < 8; ++k) {
        const int a = k & 1, b = (k >> 1) & 1, c = (k >> 2) & 1;
        const int idx = base + a + b * CODE_NUM + c * (CODE_NUM * CODE_NUM);
        const float w = wx[a] * wy[b] * wz[c];
        const float4 v = *(const float4*)(tp + ((size_t)(unsigned)(idx << 8) + cgoff));
        acc.x = fmaf(w, v.x, acc.x);
        acc.y = fmaf(w, v.y, acc.y);
        acc.z = fmaf(w, v.z, acc.z);
        acc.w = fmaf(w, v.w, acc.w);
    }
    *(float4*)(out + (size_t)p * CODE_CHANNEL + (cg << 2)) = acc;
}

// Fallback for tiny workspace: original layout, lane=channel.
__global__ __launch_bounds__(256) void interp_fallback_k(const float* __restrict__ coords,
                                                         const float* __restrict__ table,
                                                         const int* __restrict__ idxp,
                                                         float* __restrict__ out,
                                                         int npoints) {
    const int p = (int)((blockIdx.x * 256u + threadIdx.x) >> 6);
    const int lane = threadIdx.x & 63;
    if (p >= npoints) return;
    const int offset = idxp[0] * TABLE;
    const float sx = (coords[p * 3 + 0] + 1.0f) * ((CODE_NUM - 1) * 0.5f);
    const float sy = (coords[p * 3 + 1] + 1.0f) * ((CODE_NUM - 1) * 0.5f);
    const float sz = (coords[p * 3 + 2] + 1.0f) * ((CODE_NUM - 1) * 0.5f);
    const float fx = floorf(sx), fy = floorf(sy), fz = floorf(sz);
    const float rx = sx - fx, ry = sy - fy, rz = sz - fz;
    const int base = offset + (int)fx + (int)fy * CODE_NUM + (int)fz * (CODE_NUM * CODE_NUM);
    const float wx[2] = {1.0f - rx, rx};
    const float wy[2] = {1.0f - ry, ry};
    const float wz[2] = {1.0f - rz, rz};
    float acc = 0.0f;
#pragma unroll
    for (int k = 0; k < 8; ++k) {
        const int a = k & 1, b = (k >> 1) & 1, c = (k >> 2) & 1;
        const int idx = base + a + b * CODE_NUM + c * (CODE_NUM * CODE_NUM);
        acc = fmaf(wx[a] * wy[b] * wz[c], table[(size_t)lane * TABLE + idx], acc);
    }
    out[(size_t)p * CODE_CHANNEL + lane] = acc;
}

extern "C" void kernel_launch(void* const* d_in, const int* in_sizes, int n_in,
                              void* d_out, int out_size, void* d_ws, size_t ws_size,
                              hipStream_t stream) {
    const float* coords = (const float*)d_in[0];
    const float* code   = (const float*)d_in[1];
    const int*   idxp   = (const int*)d_in[2];
    float* out = (float*)d_out;

    const int npoints = in_sizes[0] / 3;  // 524288
    const size_t tbytes = (size_t)TABLE * CODE_CHANNEL * sizeof(float);  // 64 MB
    const size_t sbytes = (size_t)npoints * sizeof(float4);              // 8 MB
    const size_t need = tbytes + sbytes + 2 * NBINS * sizeof(int) + 64;

    if (ws_size >= need) {
        char* w = (char*)d_ws;
        float*  tt     = (float*)w;
        float4* sorted = (float4*)(w + tbytes);
        int*    hist   = (int*)(w + tbytes + sbytes);
        int*    cursor = hist + NBINS;
        int*    bbox   = cursor + NBINS;

        init_k<<<16, 256, 0, stream>>>(hist, bbox);
        hist_bbox_k<<<256, 256, 0, stream>>>(coords, npoints, hist, bbox);
        scan_k<<<1, 64, 0, stream>>>(hist, cursor);
        transpose_bb_k<<<TABLE / 64, 256, 0, stream>>>(code, tt, bbox);
        scatter_k<<<256, 256, 0, stream>>>(coords, npoints, cursor, sorted);
        interp4s_k<<<(npoints + 15) / 16, 256, 0, stream>>>(sorted, tt, idxp, out, npoints);
    } else if (ws_size >= tbytes) {
        float* tt = (float*)d_ws;
        transpose_k<<<TABLE / 64, 256, 0, stream>>>(code, tt);
        interp4_k<<<(npoints + 15) / 16, 256, 0, stream>>>(coords, tt, idxp, out, npoints);
    } else {
        interp_fallback_k<<<(npoints + 3) / 4, 256, 0, stream>>>(coords, code, idxp, out, npoints);
    }
}

// Round 2
// 273.583 us; speedup vs baseline: 1.3332x; 1.3332x over previous
//
#include <hip/hip_runtime.h>

// OptPosEncVol R4: spatially-sorted trilinear gather, LDS-aggregated scatter.
// R3 post-mortem: per-point global atomicAdd scatter = 114us (contention on
// ~729 hot cursor ints sharing ~81 cachelines; occupancy 10%, VALUBusy 0.3%).
// R4: two-level counting-sort scatter -- LDS histogram for local ranks, ONE
// global atomic per active bin per block, then contiguous-per-bin stores.

#define CODE_NUM 64
#define CODE_CHANNEL 64
#define TABLE (CODE_NUM * CODE_NUM * CODE_NUM)  // 262144
#define NBINS 4096                              // 16^3 coarse cells (4-cell bricks)
#define SCAT_PTS 1024                           // points per scatter block
#define SCAT_PPT 4                              // points per thread (1024/256)

// ---------------- aux: init ----------------
__global__ __launch_bounds__(256) void init_k(int* __restrict__ hist, int* __restrict__ bbox) {
    const int t = blockIdx.x * 256 + threadIdx.x;
    for (int i = t; i < NBINS; i += gridDim.x * 256) hist[i] = 0;
    if (t == 0) {
        bbox[0] = 0x7fffffff; bbox[1] = (int)0x80000000;  // ymin, ymax
        bbox[2] = 0x7fffffff; bbox[3] = (int)0x80000000;  // zmin, zmax
    }
}

__device__ __forceinline__ int cell_bin(float x, float y, float z,
                                        int& ix, int& iy, int& iz) {
    ix = (int)floorf((x + 1.0f) * ((CODE_NUM - 1) * 0.5f));
    iy = (int)floorf((y + 1.0f) * ((CODE_NUM - 1) * 0.5f));
    iz = (int)floorf((z + 1.0f) * ((CODE_NUM - 1) * 0.5f));
    const int cx = min(max(ix, 0), 63) >> 2;
    const int cy = min(max(iy, 0), 63) >> 2;
    const int cz = min(max(iz, 0), 63) >> 2;
    return cx | (cy << 4) | (cz << 8);
}

// ---------------- pass 1: histogram + bbox ----------------
__global__ __launch_bounds__(256) void hist_bbox_k(const float* __restrict__ coords, int npoints,
                                                   int* __restrict__ hist, int* __restrict__ bbox) {
    __shared__ int lh[NBINS];
    __shared__ int lb[4];
    for (int i = threadIdx.x; i < NBINS; i += 256) lh[i] = 0;
    if (threadIdx.x == 0) {
        lb[0] = 0x7fffffff; lb[1] = (int)0x80000000;
        lb[2] = 0x7fffffff; lb[3] = (int)0x80000000;
    }
    __syncthreads();
    int ymin = 0x7fffffff, ymax = (int)0x80000000;
    int zmin = 0x7fffffff, zmax = (int)0x80000000;
    const int stride = gridDim.x * 256;
    for (int p = blockIdx.x * 256 + threadIdx.x; p < npoints; p += stride) {
        const float x = coords[p * 3 + 0];
        const float y = coords[p * 3 + 1];
        const float z = coords[p * 3 + 2];
        int ix, iy, iz;
        const int bin = cell_bin(x, y, z, ix, iy, iz);
        atomicAdd(&lh[bin], 1);
        ymin = min(ymin, iy); ymax = max(ymax, iy);
        zmin = min(zmin, iz); zmax = max(zmax, iz);
    }
    atomicMin(&lb[0], ymin); atomicMax(&lb[1], ymax);
    atomicMin(&lb[2], zmin); atomicMax(&lb[3], zmax);
    __syncthreads();
    for (int i = threadIdx.x; i < NBINS; i += 256) {
        const int c = lh[i];
        if (c) atomicAdd(&hist[i], c);
    }
    if (threadIdx.x == 0) {
        atomicMin(&bbox[0], lb[0]); atomicMax(&bbox[1], lb[1]);
        atomicMin(&bbox[2], lb[2]); atomicMax(&bbox[3], lb[3]);
    }
}

// ---------------- pass 2: exclusive scan (one wave, 64 lanes x 64 bins) ----------------
__global__ __launch_bounds__(64) void scan_k(const int* __restrict__ hist, int* __restrict__ cursor) {
    const int l = threadIdx.x;  // 0..63
    int s = 0;
#pragma unroll 1
    for (int i = 0; i < 64; ++i) s += hist[l * 64 + i];
    int inc = s;
#pragma unroll
    for (int d = 1; d < 64; d <<= 1) {
        const int u = __shfl_up(inc, d, 64);
        if (l >= d) inc += u;
    }
    int run = inc - s;  // exclusive base for this lane's 64 bins
#pragma unroll 1
    for (int i = 0; i < 64; ++i) {
        cursor[l * 64 + i] = run;
        run += hist[l * 64 + i];
    }
}

// ---------------- pass 3: scatter, two-level (LDS ranks + per-bin global atomic) ----------------
__global__ __launch_bounds__(256) void scatter2_k(const float* __restrict__ coords, int npoints,
                                                  int* __restrict__ cursor,
                                                  float4* __restrict__ sorted) {
    __shared__ int lcount[NBINS];  // phase A: local counts; phase B+: global base
    for (int i = threadIdx.x; i < NBINS; i += 256) lcount[i] = 0;
    __syncthreads();

    const int p0 = blockIdx.x * SCAT_PTS;
    float px[SCAT_PPT], py[SCAT_PPT], pz[SCAT_PPT];
    int pbin[SCAT_PPT], prank[SCAT_PPT];

    // Phase A: local ranks via LDS histogram (contention ~2-3 per bin).
#pragma unroll
    for (int i = 0; i < SCAT_PPT; ++i) {
        const int p = p0 + (i << 8) + (int)threadIdx.x;
        pbin[i] = -1;
        if (p < npoints) {
            const float x = coords[p * 3 + 0];
            const float y = coords[p * 3 + 1];
            const float z = coords[p * 3 + 2];
            int ix, iy, iz;
            const int bin = cell_bin(x, y, z, ix, iy, iz);
            px[i] = x; py[i] = y; pz[i] = z;
            pbin[i] = bin;
            prank[i] = atomicAdd(&lcount[bin], 1);
        }
    }
    __syncthreads();

    // Phase B: one global atomic per active bin; overwrite count with base.
    for (int i = threadIdx.x; i < NBINS; i += 256) {
        const int c = lcount[i];
        if (c) lcount[i] = atomicAdd(&cursor[i], c);
    }
    __syncthreads();

    // Phase C: store; same-bin points from this block land contiguously.
#pragma unroll
    for (int i = 0; i < SCAT_PPT; ++i) {
        if (pbin[i] >= 0) {
            const int p = p0 + (i << 8) + (int)threadIdx.x;
            const int slot = lcount[pbin[i]] + prank[i];
            sorted[slot] = make_float4(px[i], py[i], pz[i], __int_as_float(p));
        }
    }
}

// ---------------- transpose, bbox-filtered ----------------
__global__ __launch_bounds__(256) void transpose_bb_k(const float* __restrict__ src,
                                                      float* __restrict__ dst,
                                                      const int* __restrict__ bbox) {
    const int t0 = blockIdx.x * 64;
    const int y = (t0 >> 6) & 63;
    const int z = t0 >> 12;
    if (y < bbox[0] || y > bbox[1] + 1 || z < bbox[2] || z > bbox[3] + 1) return;

    __shared__ float tile[64 * 65];
    const int j = threadIdx.x;
#pragma unroll
    for (int i = 0; i < 4; ++i) {
        const int q = (i << 8) | j;
        const int c = q >> 4;
        const int tc4 = q & 15;
        const float4 v = *(const float4*)(src + (size_t)c * TABLE + t0 + (tc4 << 2));
        tile[((tc4 << 2) + 0) * 65 + c] = v.x;
        tile[((tc4 << 2) + 1) * 65 + c] = v.y;
        tile[((tc4 << 2) + 2) * 65 + c] = v.z;
        tile[((tc4 << 2) + 3) * 65 + c] = v.w;
    }
    __syncthreads();
#pragma unroll
    for (int i = 0; i < 4; ++i) {
        const int q = (i << 8) | j;
        const int t = q >> 4;
        const int c4 = q & 15;
        float4 v;
        v.x = tile[t * 65 + (c4 << 2) + 0];
        v.y = tile[t * 65 + (c4 << 2) + 1];
        v.z = tile[t * 65 + (c4 << 2) + 2];
        v.w = tile[t * 65 + (c4 << 2) + 3];
        *(float4*)(dst + (size_t)(t0 + t) * 64 + (c4 << 2)) = v;
    }
}

// Unfiltered transpose (legacy path when ws only fits the table).
__global__ __launch_bounds__(256) void transpose_k(const float* __restrict__ src,
                                                   float* __restrict__ dst) {
    __shared__ float tile[64 * 65];
    const int t0 = blockIdx.x * 64;
    const int j = threadIdx.x;
#pragma unroll
    for (int i = 0; i < 4; ++i) {
        const int q = (i << 8) | j;
        const int c = q >> 4;
        const int tc4 = q & 15;
        const float4 v = *(const float4*)(src + (size_t)c * TABLE + t0 + (tc4 << 2));
        tile[((tc4 << 2) + 0) * 65 + c] = v.x;
        tile[((tc4 << 2) + 1) * 65 + c] = v.y;
        tile[((tc4 << 2) + 2) * 65 + c] = v.z;
        tile[((tc4 << 2) + 3) * 65 + c] = v.w;
    }
    __syncthreads();
#pragma unroll
    for (int i = 0; i < 4; ++i) {
        const int q = (i << 8) | j;
        const int t = q >> 4;
        const int c4 = q & 15;
        float4 v;
        v.x = tile[t * 65 + (c4 << 2) + 0];
        v.y = tile[t * 65 + (c4 << 2) + 1];
        v.z = tile[t * 65 + (c4 << 2) + 2];
        v.w = tile[t * 65 + (c4 << 2) + 3];
        *(float4*)(dst + (size_t)(t0 + t) * 64 + (c4 << 2)) = v;
    }
}

// ---------------- pass 4: interpolation over the sorted array ----------------
__global__ __launch_bounds__(256) void interp4s_k(const float4* __restrict__ sorted,
                                                  const float* __restrict__ table,
                                                  const int* __restrict__ idxp,
                                                  float* __restrict__ out,
                                                  int npoints) {
    unsigned bid = blockIdx.x;
    const unsigned nb = gridDim.x;
    if ((nb & 7u) == 0u) {  // XCD-chunked swizzle: each XCD owns a contiguous sorted range
        const unsigned c = nb >> 3;
        bid = (bid & 7u) * c + (bid >> 3);
    }
    const int lane = threadIdx.x & 63;
    const int sub = lane >> 4;
    const int cg = lane & 15;
    const int p = (int)(bid * 16u + ((threadIdx.x >> 6) << 2) + (unsigned)sub);
    if (p >= npoints) return;

    const int offset = idxp[0] * TABLE;
    const float4 s4 = sorted[p];
    const int op = __float_as_int(s4.w);

    const float sx = (s4.x + 1.0f) * ((CODE_NUM - 1) * 0.5f);
    const float sy = (s4.y + 1.0f) * ((CODE_NUM - 1) * 0.5f);
    const float sz = (s4.z + 1.0f) * ((CODE_NUM - 1) * 0.5f);
    const float fx = floorf(sx), fy = floorf(sy), fz = floorf(sz);
    const float rx = sx - fx, ry = sy - fy, rz = sz - fz;
    const int ix = (int)fx, iy = (int)fy, iz = (int)fz;
    const int base = offset + ix + iy * CODE_NUM + iz * (CODE_NUM * CODE_NUM);

    const float wx[2] = {1.0f - rx, rx};
    const float wy[2] = {1.0f - ry, ry};
    const float wz[2] = {1.0f - rz, rz};

    const char* tp = (const char*)table;
    const int cgoff = cg << 4;

    float4 acc = make_float4(0.f, 0.f, 0.f, 0.f);
#pragma unroll
    for (int k = 0; k < 8; ++k) {
        const int a = k & 1, b = (k >> 1) & 1, c = (k >> 2) & 1;
        const int idx = base + a + b * CODE_NUM + c * (CODE_NUM * CODE_NUM);
        const float w = wx[a] * wy[b] * wz[c];
        const float4 v = *(const float4*)(tp + ((size_t)(unsigned)(idx << 8) + cgoff));
        acc.x = fmaf(w, v.x, acc.x);
        acc.y = fmaf(w, v.y, acc.y);
        acc.z = fmaf(w, v.z, acc.z);
        acc.w = fmaf(w, v.w, acc.w);
    }
    *(float4*)(out + (size_t)op * CODE_CHANNEL + (cg << 2)) = acc;
}

// ---------------- legacy unsorted interp (ws fits table only) ----------------
__global__ __launch_bounds__(256) void interp4_k(const float* __restrict__ coords,
                                                 const float* __restrict__ table,
                                                 const int* __restrict__ idxp,
                                                 float* __restrict__ out,
                                                 int npoints) {
    const unsigned tid = blockIdx.x * 256u + threadIdx.x;
    const int lane = threadIdx.x & 63;
    const int sub = lane >> 4;
    const int cg = lane & 15;
    const int p = (int)((tid >> 6) * 4u + (unsigned)sub);
    if (p >= npoints) return;

    const int offset = idxp[0] * TABLE;
    const float sx = (coords[p * 3 + 0] + 1.0f) * ((CODE_NUM - 1) * 0.5f);
    const float sy = (coords[p * 3 + 1] + 1.0f) * ((CODE_NUM - 1) * 0.5f);
    const float sz = (coords[p * 3 + 2] + 1.0f) * ((CODE_NUM - 1) * 0.5f);
    const float fx = floorf(sx), fy = floorf(sy), fz = floorf(sz);
    const float rx = sx - fx, ry = sy - fy, rz = sz - fz;
    const int ix = (int)fx, iy = (int)fy, iz = (int)fz;
    const int base = offset + ix + iy * CODE_NUM + iz * (CODE_NUM * CODE_NUM);
    const float wx[2] = {1.0f - rx, rx};
    const float wy[2] = {1.0f - ry, ry};
    const float wz[2] = {1.0f - rz, rz};
    const char* tp = (const char*)table;
    const int cgoff = cg << 4;
    float4 acc = make_float4(0.f, 0.f, 0.f, 0.f);
#pragma unroll
    for (int k = 0; k < 8; ++k) {
        const int a = k & 1, b = (k >> 1) & 1, c = (k >> 2) & 1;
        const int idx = base + a + b * CODE_NUM + c * (CODE_NUM * CODE_NUM);
        const float w = wx[a] * wy[b] * wz[c];
        const float4 v = *(const float4*)(tp + ((size_t)(unsigned)(idx << 8) + cgoff));
        acc.x = fmaf(w, v.x, acc.x);
        acc.y = fmaf(w, v.y, acc.y);
        acc.z = fmaf(w, v.z, acc.z);
        acc.w = fmaf(w, v.w, acc.w);
    }
    *(float4*)(out + (size_t)p * CODE_CHANNEL + (cg << 2)) = acc;
}

// Fallback for tiny workspace: original layout, lane=channel.
__global__ __launch_bounds__(256) void interp_fallback_k(const float* __restrict__ coords,
                                                         const float* __restrict__ table,
                                                         const int* __restrict__ idxp,
                                                         float* __restrict__ out,
                                                         int npoints) {
    const int p = (int)((blockIdx.x * 256u + threadIdx.x) >> 6);
    const int lane = threadIdx.x & 63;
    if (p >= npoints) return;
    const int offset = idxp[0] * TABLE;
    const float sx = (coords[p * 3 + 0] + 1.0f) * ((CODE_NUM - 1) * 0.5f);
    const float sy = (coords[p * 3 + 1] + 1.0f) * ((CODE_NUM - 1) * 0.5f);
    const float sz = (coords[p * 3 + 2] + 1.0f) * ((CODE_NUM - 1) * 0.5f);
    const float fx = floorf(sx), fy = floorf(sy), fz = floorf(sz);
    const float rx = sx - fx, ry = sy - fy, rz = sz - fz;
    const int base = offset + (int)fx + (int)fy * CODE_NUM + (int)fz * (CODE_NUM * CODE_NUM);
    const float wx[2] = {1.0f - rx, rx};
    const float wy[2] = {1.0f - ry, ry};
    const float wz[2] = {1.0f - rz, rz};
    float acc = 0.0f;
#pragma unroll
    for (int k = 0; k < 8; ++k) {
        const int a = k & 1, b = (k >> 1) & 1, c = (k >> 2) & 1;
        const int idx = base + a + b * CODE_NUM + c * (CODE_NUM * CODE_NUM);
        acc = fmaf(wx[a] * wy[b] * wz[c], table[(size_t)lane * TABLE + idx], acc);
    }
    out[(size_t)p * CODE_CHANNEL + lane] = acc;
}

extern "C" void kernel_launch(void* const* d_in, const int* in_sizes, int n_in,
                              void* d_out, int out_size, void* d_ws, size_t ws_size,
                              hipStream_t stream) {
    const float* coords = (const float*)d_in[0];
    const float* code   = (const float*)d_in[1];
    const int*   idxp   = (const int*)d_in[2];
    float* out = (float*)d_out;

    const int npoints = in_sizes[0] / 3;  // 524288
    const size_t tbytes = (size_t)TABLE * CODE_CHANNEL * sizeof(float);  // 64 MB
    const size_t sbytes = (size_t)npoints * sizeof(float4);              // 8 MB
    const size_t need = tbytes + sbytes + 2 * NBINS * sizeof(int) + 64;

    if (ws_size >= need) {
        char* w = (char*)d_ws;
        float*  tt     = (float*)w;
        float4* sorted = (float4*)(w + tbytes);
        int*    hist   = (int*)(w + tbytes + sbytes);
        int*    cursor = hist + NBINS;
        int*    bbox   = cursor + NBINS;

        init_k<<<16, 256, 0, stream>>>(hist, bbox);
        hist_bbox_k<<<256, 256, 0, stream>>>(coords, npoints, hist, bbox);
        scan_k<<<1, 64, 0, stream>>>(hist, cursor);
        transpose_bb_k<<<TABLE / 64, 256, 0, stream>>>(code, tt, bbox);
        scatter2_k<<<(npoints + SCAT_PTS - 1) / SCAT_PTS, 256, 0, stream>>>(coords, npoints,
                                                                            cursor, sorted);
        interp4s_k<<<(npoints + 15) / 16, 256, 0, stream>>>(sorted, tt, idxp, out, npoints);
    } else if (ws_size >= tbytes) {
        float* tt = (float*)d_ws;
        transpose_k<<<TABLE / 64, 256, 0, stream>>>(code, tt);
        interp4_k<<<(npoints + 15) / 16, 256, 0, stream>>>(coords, tt, idxp, out, npoints);
    } else {
        interp_fallback_k<<<(npoints + 3) / 4, 256, 0, stream>>>(coords, code, idxp, out, npoints);
    }
}

// Round 4
// 272.154 us; speedup vs baseline: 1.3402x; 1.0053x over previous
//
#include <hip/hip_runtime.h>

// OptPosEncVol R5b: same as R5 (parallel scan, fused transpose+scatter,
// nontemporal write-once streams) with the nontemporal builtins fixed:
// clang's __builtin_nontemporal_* rejects HIP_vector_type float4, so use a
// native ext_vector_type(4) alias and bit-cast.

#define CODE_NUM 64
#define CODE_CHANNEL 64
#define TABLE (CODE_NUM * CODE_NUM * CODE_NUM)  // 262144
#define NBINS 4096                              // 16^3 coarse cells (4-cell bricks)
#define SCAT_PTS 1024                           // points per scatter block
#define SCAT_PPT 4                              // points per thread (1024/256)
#define TBLOCKS (TABLE / 64)                    // 4096 transpose tiles

typedef float f4_t __attribute__((ext_vector_type(4)));

__device__ __forceinline__ void nt_store_f4(float* p, float x, float y, float z, float w) {
    f4_t v = {x, y, z, w};
    __builtin_nontemporal_store(v, (f4_t*)p);
}
__device__ __forceinline__ f4_t nt_load_f4(const float* p) {
    return __builtin_nontemporal_load((const f4_t*)p);
}

// ---------------- aux: init ----------------
__global__ __launch_bounds__(256) void init_k(int* __restrict__ hist, int* __restrict__ bbox) {
    const int t = blockIdx.x * 256 + threadIdx.x;
    for (int i = t; i < NBINS; i += gridDim.x * 256) hist[i] = 0;
    if (t == 0) {
        bbox[0] = 0x7fffffff; bbox[1] = (int)0x80000000;  // ymin, ymax
        bbox[2] = 0x7fffffff; bbox[3] = (int)0x80000000;  // zmin, zmax
    }
}

__device__ __forceinline__ int cell_bin(float x, float y, float z,
                                        int& ix, int& iy, int& iz) {
    ix = (int)floorf((x + 1.0f) * ((CODE_NUM - 1) * 0.5f));
    iy = (int)floorf((y + 1.0f) * ((CODE_NUM - 1) * 0.5f));
    iz = (int)floorf((z + 1.0f) * ((CODE_NUM - 1) * 0.5f));
    const int cx = min(max(ix, 0), 63) >> 2;
    const int cy = min(max(iy, 0), 63) >> 2;
    const int cz = min(max(iz, 0), 63) >> 2;
    return cx | (cy << 4) | (cz << 8);
}

// ---------------- pass 1: histogram + bbox ----------------
__global__ __launch_bounds__(256) void hist_bbox_k(const float* __restrict__ coords, int npoints,
                                                   int* __restrict__ hist, int* __restrict__ bbox) {
    __shared__ int lh[NBINS];
    __shared__ int lb[4];
    for (int i = threadIdx.x; i < NBINS; i += 256) lh[i] = 0;
    if (threadIdx.x == 0) {
        lb[0] = 0x7fffffff; lb[1] = (int)0x80000000;
        lb[2] = 0x7fffffff; lb[3] = (int)0x80000000;
    }
    __syncthreads();
    int ymin = 0x7fffffff, ymax = (int)0x80000000;
    int zmin = 0x7fffffff, zmax = (int)0x80000000;
    const int stride = gridDim.x * 256;
    for (int p = blockIdx.x * 256 + threadIdx.x; p < npoints; p += stride) {
        const float x = coords[p * 3 + 0];
        const float y = coords[p * 3 + 1];
        const float z = coords[p * 3 + 2];
        int ix, iy, iz;
        const int bin = cell_bin(x, y, z, ix, iy, iz);
        atomicAdd(&lh[bin], 1);
        ymin = min(ymin, iy); ymax = max(ymax, iy);
        zmin = min(zmin, iz); zmax = max(zmax, iz);
    }
    atomicMin(&lb[0], ymin); atomicMax(&lb[1], ymax);
    atomicMin(&lb[2], zmin); atomicMax(&lb[3], zmax);
    __syncthreads();
    for (int i = threadIdx.x; i < NBINS; i += 256) {
        const int c = lh[i];
        if (c) atomicAdd(&hist[i], c);
    }
    if (threadIdx.x == 0) {
        atomicMin(&bbox[0], lb[0]); atomicMax(&bbox[1], lb[1]);
        atomicMin(&bbox[2], lb[2]); atomicMax(&bbox[3], lb[3]);
    }
}

// ---------------- pass 2: parallel exclusive scan (1024 threads, int4 per thread) ----------------
__global__ __launch_bounds__(1024) void scan_k(const int* __restrict__ hist,
                                               int* __restrict__ cursor) {
    const int t = threadIdx.x;      // 0..1023
    const int lane = t & 63;
    const int wid = t >> 6;         // 0..15
    const int4 h = ((const int4*)hist)[t];
    const int s = h.x + h.y + h.z + h.w;
    int inc = s;
#pragma unroll
    for (int d = 1; d < 64; d <<= 1) {
        const int u = __shfl_up(inc, d, 64);
        if (lane >= d) inc += u;
    }
    __shared__ int wsum[16];
    if (lane == 63) wsum[wid] = inc;
    __syncthreads();
    if (t < 16) {
        const int v = wsum[t];
        int winc = v;
#pragma unroll
        for (int d = 1; d < 16; d <<= 1) {
            const int u = __shfl_up(winc, d, 16);
            if (t >= d) winc += u;
        }
        wsum[t] = winc - v;  // exclusive wave base
    }
    __syncthreads();
    const int base = wsum[wid] + (inc - s);
    int4 c;
    c.x = base;
    c.y = base + h.x;
    c.z = c.y + h.y;
    c.w = c.z + h.z;
    ((int4*)cursor)[t] = c;
}

// ---------------- pass 3 (fused): transpose_bb (blocks 0..4095) + scatter (rest) ----------------
// LDS alias: transpose tile = 64*65 floats (16.64KB); scatter counts = 4096 ints (16KB).
__global__ __launch_bounds__(256) void mid_fused_k(const float* __restrict__ src,
                                                   float* __restrict__ dst,
                                                   const int* __restrict__ bbox,
                                                   const float* __restrict__ coords, int npoints,
                                                   int* __restrict__ cursor,
                                                   float4* __restrict__ sorted) {
    __shared__ int smem[64 * 65];

    if (blockIdx.x < TBLOCKS) {
        // ---- transpose tile, bbox-filtered (y/z only; x always full) ----
        const int t0 = blockIdx.x * 64;
        const int y = (t0 >> 6) & 63;
        const int z = t0 >> 12;
        if (y < bbox[0] || y > bbox[1] + 1 || z < bbox[2] || z > bbox[3] + 1) return;

        float* tile = (float*)smem;
        const int j = threadIdx.x;
#pragma unroll
        for (int i = 0; i < 4; ++i) {
            const int q = (i << 8) | j;
            const int c = q >> 4;
            const int tc4 = q & 15;
            const float4 v = *(const float4*)(src + (size_t)c * TABLE + t0 + (tc4 << 2));
            tile[((tc4 << 2) + 0) * 65 + c] = v.x;
            tile[((tc4 << 2) + 1) * 65 + c] = v.y;
            tile[((tc4 << 2) + 2) * 65 + c] = v.z;
            tile[((tc4 << 2) + 3) * 65 + c] = v.w;
        }
        __syncthreads();
#pragma unroll
        for (int i = 0; i < 4; ++i) {
            const int q = (i << 8) | j;
            const int t = q >> 4;
            const int c4 = q & 15;
            nt_store_f4(dst + (size_t)(t0 + t) * 64 + (c4 << 2),
                        tile[t * 65 + (c4 << 2) + 0],
                        tile[t * 65 + (c4 << 2) + 1],
                        tile[t * 65 + (c4 << 2) + 2],
                        tile[t * 65 + (c4 << 2) + 3]);
        }
    } else {
        // ---- two-level scatter: LDS ranks + one global atomic per active bin ----
        int* lcount = smem;
        for (int i = threadIdx.x; i < NBINS; i += 256) lcount[i] = 0;
        __syncthreads();

        const int p0 = (int)(blockIdx.x - TBLOCKS) * SCAT_PTS;
        float px[SCAT_PPT], py[SCAT_PPT], pz[SCAT_PPT];
        int pbin[SCAT_PPT], prank[SCAT_PPT];

#pragma unroll
        for (int i = 0; i < SCAT_PPT; ++i) {
            const int p = p0 + (i << 8) + (int)threadIdx.x;
            pbin[i] = -1;
            if (p < npoints) {
                const float x = coords[p * 3 + 0];
                const float y = coords[p * 3 + 1];
                const float z = coords[p * 3 + 2];
                int ix, iy, iz;
                const int bin = cell_bin(x, y, z, ix, iy, iz);
                px[i] = x; py[i] = y; pz[i] = z;
                pbin[i] = bin;
                prank[i] = atomicAdd(&lcount[bin], 1);
            }
        }
        __syncthreads();

        for (int i = threadIdx.x; i < NBINS; i += 256) {
            const int c = lcount[i];
            if (c) lcount[i] = atomicAdd(&cursor[i], c);
        }
        __syncthreads();

#pragma unroll
        for (int i = 0; i < SCAT_PPT; ++i) {
            if (pbin[i] >= 0) {
                const int p = p0 + (i << 8) + (int)threadIdx.x;
                const int slot = lcount[pbin[i]] + prank[i];
                sorted[slot] = make_float4(px[i], py[i], pz[i], __int_as_float(p));
            }
        }
    }
}

// ---------------- pass 4: interpolation over the sorted array ----------------
__global__ __launch_bounds__(256) void interp4s_k(const float4* __restrict__ sorted,
                                                  const float* __restrict__ table,
                                                  const int* __restrict__ idxp,
                                                  float* __restrict__ out,
                                                  int npoints) {
    unsigned bid = blockIdx.x;
    const unsigned nb = gridDim.x;
    if ((nb & 7u) == 0u) {  // XCD-chunked swizzle: each XCD owns a contiguous sorted range
        const unsigned c = nb >> 3;
        bid = (bid & 7u) * c + (bid >> 3);
    }
    const int lane = threadIdx.x & 63;
    const int sub = lane >> 4;
    const int cg = lane & 15;
    const int p = (int)(bid * 16u + ((threadIdx.x >> 6) << 2) + (unsigned)sub);
    if (p >= npoints) return;

    const int offset = idxp[0] * TABLE;
    const f4_t s4 = nt_load_f4((const float*)(sorted + p));
    const int op = __float_as_int(s4.w);

    const float sx = (s4.x + 1.0f) * ((CODE_NUM - 1) * 0.5f);
    const float sy = (s4.y + 1.0f) * ((CODE_NUM - 1) * 0.5f);
    const float sz = (s4.z + 1.0f) * ((CODE_NUM - 1) * 0.5f);
    const float fx = floorf(sx), fy = floorf(sy), fz = floorf(sz);
    const float rx = sx - fx, ry = sy - fy, rz = sz - fz;
    const int ix = (int)fx, iy = (int)fy, iz = (int)fz;
    const int base = offset + ix + iy * CODE_NUM + iz * (CODE_NUM * CODE_NUM);

    const float wx[2] = {1.0f - rx, rx};
    const float wy[2] = {1.0f - ry, ry};
    const float wz[2] = {1.0f - rz, rz};

    const char* tp = (const char*)table;
    const int cgoff = cg << 4;

    float4 acc = make_float4(0.f, 0.f, 0.f, 0.f);
#pragma unroll
    for (int k = 0; k < 8; ++k) {
        const int a = k & 1, b = (k >> 1) & 1, c = (k >> 2) & 1;
        const int idx = base + a + b * CODE_NUM + c * (CODE_NUM * CODE_NUM);
        const float w = wx[a] * wy[b] * wz[c];
        const float4 v = *(const float4*)(tp + ((size_t)(unsigned)(idx << 8) + cgoff));
        acc.x = fmaf(w, v.x, acc.x);
        acc.y = fmaf(w, v.y, acc.y);
        acc.z = fmaf(w, v.z, acc.z);
        acc.w = fmaf(w, v.w, acc.w);
    }
    // write-once 134MB stream: nontemporal, keep L2 for the table hot-set
    nt_store_f4(out + (size_t)op * CODE_CHANNEL + (cg << 2), acc.x, acc.y, acc.z, acc.w);
}

// ---------------- legacy paths (smaller workspace tiers) ----------------
__global__ __launch_bounds__(256) void transpose_k(const float* __restrict__ src,
                                                   float* __restrict__ dst) {
    __shared__ float tile[64 * 65];
    const int t0 = blockIdx.x * 64;
    const int j = threadIdx.x;
#pragma unroll
    for (int i = 0; i < 4; ++i) {
        const int q = (i << 8) | j;
        const int c = q >> 4;
        const int tc4 = q & 15;
        const float4 v = *(const float4*)(src + (size_t)c * TABLE + t0 + (tc4 << 2));
        tile[((tc4 << 2) + 0) * 65 + c] = v.x;
        tile[((tc4 << 2) + 1) * 65 + c] = v.y;
        tile[((tc4 << 2) + 2) * 65 + c] = v.z;
        tile[((tc4 << 2) + 3) * 65 + c] = v.w;
    }
    __syncthreads();
#pragma unroll
    for (int i = 0; i < 4; ++i) {
        const int q = (i << 8) | j;
        const int t = q >> 4;
        const int c4 = q & 15;
        float4 v;
        v.x = tile[t * 65 + (c4 << 2) + 0];
        v.y = tile[t * 65 + (c4 << 2) + 1];
        v.z = tile[t * 65 + (c4 << 2) + 2];
        v.w = tile[t * 65 + (c4 << 2) + 3];
        *(float4*)(dst + (size_t)(t0 + t) * 64 + (c4 << 2)) = v;
    }
}

__global__ __launch_bounds__(256) void interp4_k(const float* __restrict__ coords,
                                                 const float* __restrict__ table,
                                                 const int* __restrict__ idxp,
                                                 float* __restrict__ out,
                                                 int npoints) {
    const unsigned tid = blockIdx.x * 256u + threadIdx.x;
    const int lane = threadIdx.x & 63;
    const int sub = lane >> 4;
    const int cg = lane & 15;
    const int p = (int)((tid >> 6) * 4u + (unsigned)sub);
    if (p >= npoints) return;

    const int offset = idxp[0] * TABLE;
    const float sx = (coords[p * 3 + 0] + 1.0f) * ((CODE_NUM - 1) * 0.5f);
    const float sy = (coords[p * 3 + 1] + 1.0f) * ((CODE_NUM - 1) * 0.5f);
    const float sz = (coords[p * 3 + 2] + 1.0f) * ((CODE_NUM - 1) * 0.5f);
    const float fx = floorf(sx), fy = floorf(sy), fz = floorf(sz);
    const float rx = sx - fx, ry = sy - fy, rz = sz - fz;
    const int ix = (int)fx, iy = (int)fy, iz = (int)fz;
    const int base = offset + ix + iy * CODE_NUM + iz * (CODE_NUM * CODE_NUM);
    const float wx[2] = {1.0f - rx, rx};
    const float wy[2] = {1.0f - ry, ry};
    const float wz[2] = {1.0f - rz, rz};
    const char* tp = (const char*)table;
    const int cgoff = cg << 4;
    float4 acc = make_float4(0.f, 0.f, 0.f, 0.f);
#pragma unroll
    for (int k = 0; k < 8; ++k) {
        const int a = k & 1, b = (k >> 1) & 1, c = (k >> 2) & 1;
        const int idx = base + a + b * CODE_NUM + c * (CODE_NUM * CODE_NUM);
        const float w = wx[a] * wy[b] * wz[c];
        const float4 v = *(const float4*)(tp + ((size_t)(unsigned)(idx << 8) + cgoff));
        acc.x = fmaf(w, v.x, acc.x);
        acc.y = fmaf(w, v.y, acc.y);
        acc.z = fmaf(w, v.z, acc.z);
        acc.w = fmaf(w, v.w, acc.w);
    }
    *(float4*)(out + (size_t)p * CODE_CHANNEL + (cg << 2)) = acc;
}

__global__ __launch_bounds__(256) void interp_fallback_k(const float* __restrict__ coords,
                                                         const float* __restrict__ table,
                                                         const int* __restrict__ idxp,
                                                         float* __restrict__ out,
                                                         int npoints) {
    const int p = (int)((blockIdx.x * 256u + threadIdx.x) >> 6);
    const int lane = threadIdx.x & 63;
    if (p >= npoints) return;
    const int offset = idxp[0] * TABLE;
    const float sx = (coords[p * 3 + 0] + 1.0f) * ((CODE_NUM - 1) * 0.5f);
    const float sy = (coords[p * 3 + 1] + 1.0f) * ((CODE_NUM - 1) * 0.5f);
    const float sz = (coords[p * 3 + 2] + 1.0f) * ((CODE_NUM - 1) * 0.5f);
    const float fx = floorf(sx), fy = floorf(sy), fz = floorf(sz);
    const float rx = sx - fx, ry = sy - fy, rz = sz - fz;
    const int base = offset + (int)fx + (int)fy * CODE_NUM + (int)fz * (CODE_NUM * CODE_NUM);
    const float wx[2] = {1.0f - rx, rx};
    const float wy[2] = {1.0f - ry, ry};
    const float wz[2] = {1.0f - rz, rz};
    float acc = 0.0f;
#pragma unroll
    for (int k = 0; k < 8; ++k) {
        const int a = k & 1, b = (k >> 1) & 1, c = (k >> 2) & 1;
        const int idx = base + a + b * CODE_NUM + c * (CODE_NUM * CODE_NUM);
        acc = fmaf(wx[a] * wy[b] * wz[c], table[(size_t)lane * TABLE + idx], acc);
    }
    out[(size_t)p * CODE_CHANNEL + lane] = acc;
}

extern "C" void kernel_launch(void* const* d_in, const int* in_sizes, int n_in,
                              void* d_out, int out_size, void* d_ws, size_t ws_size,
                              hipStream_t stream) {
    const float* coords = (const float*)d_in[0];
    const float* code   = (const float*)d_in[1];
    const int*   idxp   = (const int*)d_in[2];
    float* out = (float*)d_out;

    const int npoints = in_sizes[0] / 3;  // 524288
    const size_t tbytes = (size_t)TABLE * CODE_CHANNEL * sizeof(float);  // 64 MB
    const size_t sbytes = (size_t)npoints * sizeof(float4);              // 8 MB
    const size_t need = tbytes + sbytes + 2 * NBINS * sizeof(int) + 64;

    if (ws_size >= need) {
        char* w = (char*)d_ws;
        float*  tt     = (float*)w;
        float4* sorted = (float4*)(w + tbytes);
        int*    hist   = (int*)(w + tbytes + sbytes);
        int*    cursor = hist + NBINS;
        int*    bbox   = cursor + NBINS;

        const int nscat = (npoints + SCAT_PTS - 1) / SCAT_PTS;

        init_k<<<16, 256, 0, stream>>>(hist, bbox);
        hist_bbox_k<<<256, 256, 0, stream>>>(coords, npoints, hist, bbox);
        scan_k<<<1, 1024, 0, stream>>>(hist, cursor);
        mid_fused_k<<<TBLOCKS + nscat, 256, 0, stream>>>(code, tt, bbox,
                                                         coords, npoints, cursor, sorted);
        interp4s_k<<<(npoints + 15) / 16, 256, 0, stream>>>(sorted, tt, idxp, out, npoints);
    } else if (ws_size >= tbytes) {
        float* tt = (float*)d_ws;
        transpose_k<<<TABLE / 64, 256, 0, stream>>>(code, tt);
        interp4_k<<<(npoints + 15) / 16, 256, 0, stream>>>(coords, tt, idxp, out, npoints);
    } else {
        interp_fallback_k<<<(npoints + 3) / 4, 256, 0, stream>>>(coords, code, idxp, out, npoints);
    }
}